// Round 14
// baseline (174.317 us; speedup 1.0000x reference)
//
#include <hip/hip_runtime.h>
#include <hip/hip_bf16.h>

#define B_    8
#define C_    192
#define N_    3136
#define K_    9
#define OC    192
#define KDIM  384                 // 2*C
#define ROWS  (B_ * N_)           // 25088
#define BNK   (B_ * N_ * K_)      // 225792

typedef __hip_bfloat16 bf16;
using short8 = __attribute__((ext_vector_type(8))) short;
using us4    = __attribute__((ext_vector_type(4))) unsigned short;
using f32x4  = __attribute__((ext_vector_type(4))) float;

__device__ inline float bfbits2f(unsigned short u) {
    unsigned int x = ((unsigned int)u) << 16;
    return __builtin_bit_cast(float, x);
}
__device__ inline bf16 f2bf(float v) { return __float2bfloat16(v); }
__device__ inline unsigned short f2bfbits(float v) {
    bf16 t = __float2bfloat16(v);
    return *reinterpret_cast<unsigned short*>(&t);
}

// ---------------------------------------------------------------------------
// Kernel 1: transpose x,y (B,C,N) fp32 -> (B,N,C) bf16 (x into h's first half,
// y into yT). blockIdx.z==16 slice: W fp32->bf16 and stats zeroing.
// (verbatim from round-10 PASSED source)
// ---------------------------------------------------------------------------
__global__ void k_prep(const float* __restrict__ x, const float* __restrict__ y,
                       const float* __restrict__ W,
                       bf16* __restrict__ h, bf16* __restrict__ yT,
                       bf16* __restrict__ Wb, float* __restrict__ stats) {
    int tx = threadIdx.x, ty = threadIdx.y;
    int bz = blockIdx.z;
    if (bz == 16) {
        int flat = blockIdx.y * 98 + blockIdx.x;
        int t = ty * 32 + tx;
        if (flat < 288) {                       // 288*256 = 73728 = OC*KDIM
            int i = flat * 256 + t;
            Wb[i] = f2bf(W[i]);
        }
        if (flat == 0) stats[t] = 0.f;          // t in [0,256)
        if (flat == 1 && t < 128) stats[256 + t] = 0.f;
        return;
    }
    __shared__ float tile[32][33];
    int n0 = blockIdx.x * 32, c0 = blockIdx.y * 32;
    int b = bz >> 1, which = bz & 1;
    const float* src = which ? y : x;
#pragma unroll
    for (int i = 0; i < 4; i++) {
        int c = c0 + ty + i * 8;
        tile[ty + i * 8][tx] = src[((size_t)b * C_ + c) * N_ + n0 + tx];
    }
    __syncthreads();
    if (which == 0) {
#pragma unroll
        for (int i = 0; i < 4; i++) {
            int n = n0 + ty + i * 8;
            h[((size_t)b * N_ + n) * KDIM + c0 + tx] = f2bf(tile[tx][ty + i * 8]);
        }
    } else {
#pragma unroll
        for (int i = 0; i < 4; i++) {
            int n = n0 + ty + i * 8;
            yT[((size_t)b * N_ + n) * C_ + c0 + tx] = f2bf(tile[tx][ty + i * 8]);
        }
    }
}

// ---------------------------------------------------------------------------
// Kernel 2: fused gather + stats GEMM. Per block (64 rows):
//  (a) each wave gathers rel for 16 rows -> h second half (us4 writes)
//  (b) __syncthreads
//  (c) GEMM h·W^T over the same 64 rows -> per-channel sum/sumsq atomics.
// h-right reads in (c) hit L2 (just written by this block).
// ---------------------------------------------------------------------------
__launch_bounds__(256)
__global__ void k_gather_stats(const int* __restrict__ ei, bf16* __restrict__ h,
                               const bf16* __restrict__ yT,
                               const bf16* __restrict__ Wb,
                               float* __restrict__ stats) {
    const int tid = threadIdx.x;
    const int wave = tid >> 6, lane = tid & 63;
    const int r0 = blockIdx.x * 64;

    // ---- (a) gather: wave handles rows r0+wave*16 .. +15 ----
    {
        const int rbase = r0 + wave * 16;
        for (int rr = 0; rr < 16; rr++) {
            int r = rbase + rr;
            int bb = r / N_;
            const int* e0 = ei + (size_t)r * K_;               // gathers y
            const int* e1 = ei + (size_t)BNK + (size_t)r * K_; // gathers x
            int ej[K_], ex[K_];
#pragma unroll
            for (int k = 0; k < K_; k++) { ej[k] = e0[k]; ex[k] = e1[k]; }

            const us4* y4 = (const us4*)(yT + (size_t)bb * N_ * C_);   // 48 us4/row
            const us4* x4 = (const us4*)(h + (size_t)bb * N_ * KDIM);  // 96 us4/row

            if (lane < 48) {
                float m0 = -3.4e38f, m1 = -3.4e38f, m2 = -3.4e38f, m3 = -3.4e38f;
#pragma unroll
                for (int k = 0; k < K_; k++) {
                    us4 vy = y4[(size_t)ej[k] * 48 + lane];
                    us4 vx = x4[(size_t)ex[k] * 96 + lane];
                    m0 = fmaxf(m0, bfbits2f(vy.x) - bfbits2f(vx.x));
                    m1 = fmaxf(m1, bfbits2f(vy.y) - bfbits2f(vx.y));
                    m2 = fmaxf(m2, bfbits2f(vy.z) - bfbits2f(vx.z));
                    m3 = fmaxf(m3, bfbits2f(vy.w) - bfbits2f(vx.w));
                }
                us4 o;
                o.x = f2bfbits(m0); o.y = f2bfbits(m1);
                o.z = f2bfbits(m2); o.w = f2bfbits(m3);
                *((us4*)(h + (size_t)r * KDIM + C_) + lane) = o;
            }
        }
    }
    __syncthreads();

    // ---- (c) stats GEMM (round-10 k_gemm_stats body, 4 waves x 48 o-cols) ----
    {
        const int fcol = lane & 15, fgrp = lane >> 4;
        const int colbase = wave * 48;
        f32x4 acc[4][3] = {};
        for (int kk = 0; kk < 12; kk++) {
            short8 a[4], bb[3];
#pragma unroll
            for (int i = 0; i < 4; i++)
                a[i] = *reinterpret_cast<const short8*>(
                    h + (size_t)(r0 + i * 16 + fcol) * KDIM + kk * 32 + fgrp * 8);
#pragma unroll
            for (int j = 0; j < 3; j++)
                bb[j] = *reinterpret_cast<const short8*>(
                    Wb + (size_t)(colbase + j * 16 + fcol) * KDIM + kk * 32 + fgrp * 8);
#pragma unroll
            for (int i = 0; i < 4; i++)
#pragma unroll
                for (int j = 0; j < 3; j++)
                    acc[i][j] = __builtin_amdgcn_mfma_f32_16x16x32_bf16(a[i], bb[j], acc[i][j], 0, 0, 0);
        }
#pragma unroll
        for (int j = 0; j < 3; j++) {
            int o = colbase + j * 16 + fcol;
            float s1 = 0.f, s2 = 0.f;
#pragma unroll
            for (int i = 0; i < 4; i++)
#pragma unroll
                for (int e = 0; e < 4; e++) {
                    float v = acc[i][j][e];
                    s1 += v;
                    s2 += v * v;
                }
            s1 += __shfl_xor(s1, 16); s1 += __shfl_xor(s1, 32);
            s2 += __shfl_xor(s2, 16); s2 += __shfl_xor(s2, 32);
            if (fgrp == 0) {
                atomicAdd(&stats[o], s1);
                atomicAdd(&stats[OC + o], s2);
            }
        }
    }
}

// ---------------------------------------------------------------------------
// Kernel 3: GEMM pass 2 (operand-swapped: A=W rows->D rows = o,
// B=h rows->D cols = n) + BN + exact GELU, storing out (b,o,n) coalesced.
// (verbatim from round-10 PASSED source)
// ---------------------------------------------------------------------------
__launch_bounds__(192)
__global__ void k_gemm_bn(const bf16* __restrict__ h, const bf16* __restrict__ Wb,
                          const float* __restrict__ stats,
                          const float* __restrict__ gamma, const float* __restrict__ beta,
                          float* __restrict__ out) {
    int tid = threadIdx.x;
    int wave = tid >> 6, lane = tid & 63;
    int fcol = lane & 15, fgrp = lane >> 4;
    int r0 = blockIdx.x * 64;            // 64 rows within one batch (3136 % 64 == 0)
    int b = r0 / N_;
    int n0 = r0 % N_;
    int colbase = wave * 64;

    f32x4 acc[4][4] = {};

    for (int kk = 0; kk < 12; kk++) {
        short8 wfr[4], hfr[4];
#pragma unroll
        for (int i = 0; i < 4; i++)
            wfr[i] = *reinterpret_cast<const short8*>(
                Wb + (size_t)(colbase + i * 16 + fcol) * KDIM + kk * 32 + fgrp * 8);
#pragma unroll
        for (int j = 0; j < 4; j++)
            hfr[j] = *reinterpret_cast<const short8*>(
                h + (size_t)(r0 + j * 16 + fcol) * KDIM + kk * 32 + fgrp * 8);
#pragma unroll
        for (int i = 0; i < 4; i++)
#pragma unroll
            for (int j = 0; j < 4; j++)
                acc[i][j] = __builtin_amdgcn_mfma_f32_16x16x32_bf16(wfr[i], hfr[j], acc[i][j], 0, 0, 0);
    }

    const float invc = 1.0f / (float)ROWS;
#pragma unroll
    for (int i = 0; i < 4; i++) {
#pragma unroll
        for (int e = 0; e < 4; e++) {
            int o = colbase + i * 16 + fgrp * 4 + e;   // D row
            float mean = stats[o] * invc;
            float var  = stats[OC + o] * invc - mean * mean;
            float is   = rsqrtf(var + 1e-5f);
            float sc = gamma[o] * is;
            float sh = beta[o] - mean * sc;
#pragma unroll
            for (int j = 0; j < 4; j++) {
                float z = acc[i][j][e] * sc + sh;
                float gl = 0.5f * z * (1.0f + erff(z * 0.70710678118654752f));
                out[((size_t)b * OC + o) * N_ + n0 + j * 16 + fcol] = gl;
            }
        }
    }
}

// ---------------------------------------------------------------------------
extern "C" void kernel_launch(void* const* d_in, const int* in_sizes, int n_in,
                              void* d_out, int out_size, void* d_ws, size_t ws_size,
                              hipStream_t stream) {
    const float* x     = (const float*)d_in[0];
    const float* y     = (const float*)d_in[1];
    const int*   ei    = (const int*)d_in[2];
    const float* W     = (const float*)d_in[3];
    const float* gamma = (const float*)d_in[4];
    const float* beta  = (const float*)d_in[5];
    float* out = (float*)d_out;

    char* ws = (char*)d_ws;
    // layout:
    //   h     : ROWS*384 bf16 = 19,267,584 B  (first half x, second half rel)
    //   yT    : ROWS*192 bf16 =  9,633,792 B
    //   Wb    : 192*384  bf16 =    147,456 B
    //   stats : 384 fp32      =      1,536 B
    bf16*  h     = (bf16*)(ws);
    bf16*  yT    = (bf16*)(ws + 19267584);
    bf16*  Wb    = (bf16*)(ws + 19267584 + 9633792);
    float* stats = (float*)(ws + 19267584 + 9633792 + 147456);

    dim3 bt(32, 8);
    k_prep<<<dim3(N_ / 32, C_ / 32, 2 * B_ + 1), bt, 0, stream>>>(x, y, W, h, yT, Wb, stats);
    k_gather_stats<<<ROWS / 64, 256, 0, stream>>>(ei, h, yT, Wb, stats);
    k_gemm_bn<<<ROWS / 64, 192, 0, stream>>>(h, Wb, stats, gamma, beta, out);
}

// Round 15
// 165.821 us; speedup vs baseline: 1.0512x; 1.0512x over previous
//
#include <hip/hip_runtime.h>
#include <hip/hip_bf16.h>

#define B_    8
#define C_    192
#define N_    3136
#define K_    9
#define OC    192
#define KDIM  384                 // 2*C
#define ROWS  (B_ * N_)           // 25088
#define BNK   (B_ * N_ * K_)      // 225792

typedef __hip_bfloat16 bf16;
using short8 = __attribute__((ext_vector_type(8))) short;
using us4    = __attribute__((ext_vector_type(4))) unsigned short;
using f32x4  = __attribute__((ext_vector_type(4))) float;

__device__ inline float bfbits2f(unsigned short u) {
    unsigned int x = ((unsigned int)u) << 16;
    return __builtin_bit_cast(float, x);
}
__device__ inline bf16 f2bf(float v) { return __float2bfloat16(v); }
__device__ inline unsigned short f2bfbits(float v) {
    bf16 t = __float2bfloat16(v);
    return *reinterpret_cast<unsigned short*>(&t);
}

// ---------------------------------------------------------------------------
// Kernel 1: transpose x,y (B,C,N) fp32 -> (B,N,C) bf16 (x into h's first half,
// y into yT). blockIdx.z==16 slice: W fp32->bf16 and stats zeroing.
// (verbatim round-10 PASSED)
// ---------------------------------------------------------------------------
__global__ void k_prep(const float* __restrict__ x, const float* __restrict__ y,
                       const float* __restrict__ W,
                       bf16* __restrict__ h, bf16* __restrict__ yT,
                       bf16* __restrict__ Wb, float* __restrict__ stats) {
    int tx = threadIdx.x, ty = threadIdx.y;
    int bz = blockIdx.z;
    if (bz == 16) {
        int flat = blockIdx.y * 98 + blockIdx.x;
        int t = ty * 32 + tx;
        if (flat < 288) {                       // 288*256 = 73728 = OC*KDIM
            int i = flat * 256 + t;
            Wb[i] = f2bf(W[i]);
        }
        if (flat == 0) stats[t] = 0.f;          // t in [0,256)
        if (flat == 1 && t < 128) stats[256 + t] = 0.f;
        return;
    }
    __shared__ float tile[32][33];
    int n0 = blockIdx.x * 32, c0 = blockIdx.y * 32;
    int b = bz >> 1, which = bz & 1;
    const float* src = which ? y : x;
#pragma unroll
    for (int i = 0; i < 4; i++) {
        int c = c0 + ty + i * 8;
        tile[ty + i * 8][tx] = src[((size_t)b * C_ + c) * N_ + n0 + tx];
    }
    __syncthreads();
    if (which == 0) {
#pragma unroll
        for (int i = 0; i < 4; i++) {
            int n = n0 + ty + i * 8;
            h[((size_t)b * N_ + n) * KDIM + c0 + tx] = f2bf(tile[tx][ty + i * 8]);
        }
    } else {
#pragma unroll
        for (int i = 0; i < 4; i++) {
            int n = n0 + ty + i * 8;
            yT[((size_t)b * N_ + n) * C_ + c0 + tx] = f2bf(tile[tx][ty + i * 8]);
        }
    }
}

// ---------------------------------------------------------------------------
// Kernel 2: gather + rel max, one wave per row, XCD-aware batch swizzle:
// b = bid & 7 so (with round-robin block->XCD dispatch) each XCD touches only
// one batch's x/yT rows (~2.4 MB hot) -> L2-resident gather.
// ---------------------------------------------------------------------------
__launch_bounds__(256)
__global__ void k_gather_rel(const int* __restrict__ ei, bf16* __restrict__ h,
                             const bf16* __restrict__ yT) {
    const int wave = threadIdx.x >> 6;
    const int lane = threadIdx.x & 63;
    const int b   = blockIdx.x & 7;              // batch pinned per XCD
    const int n   = (blockIdx.x >> 3) * 4 + wave; // 784 groups * 4 waves = 3136
    const int r   = b * N_ + n;

    const int* e0 = ei + (size_t)r * K_;               // edge_index[0] -> gathers y
    const int* e1 = ei + (size_t)BNK + (size_t)r * K_; // edge_index[1] -> gathers x
    int ej[K_], ex[K_];
#pragma unroll
    for (int k = 0; k < K_; k++) { ej[k] = e0[k]; ex[k] = e1[k]; }

    const us4* y4 = (const us4*)(yT + (size_t)b * N_ * C_);   // 48 us4/row
    const us4* x4 = (const us4*)(h + (size_t)b * N_ * KDIM);  // 96 us4/row

    if (lane < 48) {
        float m0 = -3.4e38f, m1 = -3.4e38f, m2 = -3.4e38f, m3 = -3.4e38f;
#pragma unroll
        for (int k = 0; k < K_; k++) {
            us4 vy = y4[(size_t)ej[k] * 48 + lane];
            us4 vx = x4[(size_t)ex[k] * 96 + lane];
            m0 = fmaxf(m0, bfbits2f(vy.x) - bfbits2f(vx.x));
            m1 = fmaxf(m1, bfbits2f(vy.y) - bfbits2f(vx.y));
            m2 = fmaxf(m2, bfbits2f(vy.z) - bfbits2f(vx.z));
            m3 = fmaxf(m3, bfbits2f(vy.w) - bfbits2f(vx.w));
        }
        us4 o;
        o.x = f2bfbits(m0); o.y = f2bfbits(m1);
        o.z = f2bfbits(m2); o.w = f2bfbits(m3);
        *((us4*)(h + (size_t)r * KDIM + C_) + lane) = o;
    }
}

// ---------------------------------------------------------------------------
// Kernel 3: GEMM pass 1 — per-channel sum / sumsq only (no output store).
// (verbatim round-10 PASSED)
// ---------------------------------------------------------------------------
__launch_bounds__(192)
__global__ void k_gemm_stats(const bf16* __restrict__ h, const bf16* __restrict__ Wb,
                             float* __restrict__ stats) {
    int tid = threadIdx.x;
    int wave = tid >> 6, lane = tid & 63;
    int fcol = lane & 15, fgrp = lane >> 4;
    int r0 = blockIdx.x * 64;
    int colbase = wave * 64;

    f32x4 acc[4][4] = {};

    for (int kk = 0; kk < 12; kk++) {
        short8 a[4], bb[4];
#pragma unroll
        for (int i = 0; i < 4; i++)
            a[i] = *reinterpret_cast<const short8*>(
                h + (size_t)(r0 + i * 16 + fcol) * KDIM + kk * 32 + fgrp * 8);
#pragma unroll
        for (int j = 0; j < 4; j++)
            bb[j] = *reinterpret_cast<const short8*>(
                Wb + (size_t)(colbase + j * 16 + fcol) * KDIM + kk * 32 + fgrp * 8);
#pragma unroll
        for (int i = 0; i < 4; i++)
#pragma unroll
            for (int j = 0; j < 4; j++)
                acc[i][j] = __builtin_amdgcn_mfma_f32_16x16x32_bf16(a[i], bb[j], acc[i][j], 0, 0, 0);
    }

#pragma unroll
    for (int j = 0; j < 4; j++) {
        int o = colbase + j * 16 + fcol;
        float s1 = 0.f, s2 = 0.f;
#pragma unroll
        for (int i = 0; i < 4; i++)
#pragma unroll
            for (int e = 0; e < 4; e++) {
                float v = acc[i][j][e];
                s1 += v;
                s2 += v * v;
            }
        s1 += __shfl_xor(s1, 16); s1 += __shfl_xor(s1, 32);
        s2 += __shfl_xor(s2, 16); s2 += __shfl_xor(s2, 32);
        if (fgrp == 0) {
            atomicAdd(&stats[o], s1);
            atomicAdd(&stats[OC + o], s2);
        }
    }
}

// ---------------------------------------------------------------------------
// Kernel 4: GEMM pass 2 (operand-swapped) + BN + exact GELU -> out (b,o,n).
// (verbatim round-10 PASSED)
// ---------------------------------------------------------------------------
__launch_bounds__(192)
__global__ void k_gemm_bn(const bf16* __restrict__ h, const bf16* __restrict__ Wb,
                          const float* __restrict__ stats,
                          const float* __restrict__ gamma, const float* __restrict__ beta,
                          float* __restrict__ out) {
    int tid = threadIdx.x;
    int wave = tid >> 6, lane = tid & 63;
    int fcol = lane & 15, fgrp = lane >> 4;
    int r0 = blockIdx.x * 64;            // 64 rows within one batch (3136 % 64 == 0)
    int b = r0 / N_;
    int n0 = r0 % N_;
    int colbase = wave * 64;

    f32x4 acc[4][4] = {};

    for (int kk = 0; kk < 12; kk++) {
        short8 wfr[4], hfr[4];
#pragma unroll
        for (int i = 0; i < 4; i++)
            wfr[i] = *reinterpret_cast<const short8*>(
                Wb + (size_t)(colbase + i * 16 + fcol) * KDIM + kk * 32 + fgrp * 8);
#pragma unroll
        for (int j = 0; j < 4; j++)
            hfr[j] = *reinterpret_cast<const short8*>(
                h + (size_t)(r0 + j * 16 + fcol) * KDIM + kk * 32 + fgrp * 8);
#pragma unroll
        for (int i = 0; i < 4; i++)
#pragma unroll
            for (int j = 0; j < 4; j++)
                acc[i][j] = __builtin_amdgcn_mfma_f32_16x16x32_bf16(wfr[i], hfr[j], acc[i][j], 0, 0, 0);
    }

    const float invc = 1.0f / (float)ROWS;
#pragma unroll
    for (int i = 0; i < 4; i++) {
#pragma unroll
        for (int e = 0; e < 4; e++) {
            int o = colbase + i * 16 + fgrp * 4 + e;   // D row
            float mean = stats[o] * invc;
            float var  = stats[OC + o] * invc - mean * mean;
            float is   = rsqrtf(var + 1e-5f);
            float sc = gamma[o] * is;
            float sh = beta[o] - mean * sc;
#pragma unroll
            for (int j = 0; j < 4; j++) {
                float z = acc[i][j][e] * sc + sh;
                float gl = 0.5f * z * (1.0f + erff(z * 0.70710678118654752f));
                out[((size_t)b * OC + o) * N_ + n0 + j * 16 + fcol] = gl;
            }
        }
    }
}

// ---------------------------------------------------------------------------
extern "C" void kernel_launch(void* const* d_in, const int* in_sizes, int n_in,
                              void* d_out, int out_size, void* d_ws, size_t ws_size,
                              hipStream_t stream) {
    const float* x     = (const float*)d_in[0];
    const float* y     = (const float*)d_in[1];
    const int*   ei    = (const int*)d_in[2];
    const float* W     = (const float*)d_in[3];
    const float* gamma = (const float*)d_in[4];
    const float* beta  = (const float*)d_in[5];
    float* out = (float*)d_out;

    char* ws = (char*)d_ws;
    // layout:
    //   h     : ROWS*384 bf16 = 19,267,584 B  (first half x, second half rel)
    //   yT    : ROWS*192 bf16 =  9,633,792 B
    //   Wb    : 192*384  bf16 =    147,456 B
    //   stats : 384 fp32      =      1,536 B
    bf16*  h     = (bf16*)(ws);
    bf16*  yT    = (bf16*)(ws + 19267584);
    bf16*  Wb    = (bf16*)(ws + 19267584 + 9633792);
    float* stats = (float*)(ws + 19267584 + 9633792 + 147456);

    dim3 bt(32, 8);
    k_prep<<<dim3(N_ / 32, C_ / 32, 2 * B_ + 1), bt, 0, stream>>>(x, y, W, h, yT, Wb, stats);
    k_gather_rel<<<ROWS / 4, 256, 0, stream>>>(ei, h, yT);
    k_gemm_stats<<<ROWS / 64, 192, 0, stream>>>(h, Wb, stats);
    k_gemm_bn<<<ROWS / 64, 192, 0, stream>>>(h, Wb, stats, gamma, beta, out);
}

// Round 16
// 149.426 us; speedup vs baseline: 1.1666x; 1.1097x over previous
//
#include <hip/hip_runtime.h>
#include <hip/hip_bf16.h>

#define B_    8
#define C_    192
#define N_    3136
#define K_    9
#define OC    192
#define KDIM  384                 // 2*C
#define ROWS  (B_ * N_)           // 25088
#define BNK   (B_ * N_ * K_)      // 225792

typedef __hip_bfloat16 bf16;
using short8 = __attribute__((ext_vector_type(8))) short;
using us4    = __attribute__((ext_vector_type(4))) unsigned short;
using f32x4  = __attribute__((ext_vector_type(4))) float;

__device__ inline float bfbits2f(unsigned short u) {
    unsigned int x = ((unsigned int)u) << 16;
    return __builtin_bit_cast(float, x);
}
__device__ inline bf16 f2bf(float v) { return __float2bfloat16(v); }
__device__ inline unsigned short f2bfbits(float v) {
    bf16 t = __float2bfloat16(v);
    return *reinterpret_cast<unsigned short*>(&t);
}

// ---------------------------------------------------------------------------
// Kernel 1: transpose x,y (B,C,N) fp32 -> (B,N,C) bf16 (x into h's first half,
// y into yT). blockIdx.z==16 slice: W fp32->bf16 and stats zeroing.
// (verbatim R15 PASSED)
// ---------------------------------------------------------------------------
__global__ void k_prep(const float* __restrict__ x, const float* __restrict__ y,
                       const float* __restrict__ W,
                       bf16* __restrict__ h, bf16* __restrict__ yT,
                       bf16* __restrict__ Wb, float* __restrict__ stats) {
    int tx = threadIdx.x, ty = threadIdx.y;
    int bz = blockIdx.z;
    if (bz == 16) {
        int flat = blockIdx.y * 98 + blockIdx.x;
        int t = ty * 32 + tx;
        if (flat < 288) {                       // 288*256 = 73728 = OC*KDIM
            int i = flat * 256 + t;
            Wb[i] = f2bf(W[i]);
        }
        if (flat == 0) stats[t] = 0.f;          // t in [0,256)
        if (flat == 1 && t < 128) stats[256 + t] = 0.f;
        return;
    }
    __shared__ float tile[32][33];
    int n0 = blockIdx.x * 32, c0 = blockIdx.y * 32;
    int b = bz >> 1, which = bz & 1;
    const float* src = which ? y : x;
#pragma unroll
    for (int i = 0; i < 4; i++) {
        int c = c0 + ty + i * 8;
        tile[ty + i * 8][tx] = src[((size_t)b * C_ + c) * N_ + n0 + tx];
    }
    __syncthreads();
    if (which == 0) {
#pragma unroll
        for (int i = 0; i < 4; i++) {
            int n = n0 + ty + i * 8;
            h[((size_t)b * N_ + n) * KDIM + c0 + tx] = f2bf(tile[tx][ty + i * 8]);
        }
    } else {
#pragma unroll
        for (int i = 0; i < 4; i++) {
            int n = n0 + ty + i * 8;
            yT[((size_t)b * N_ + n) * C_ + c0 + tx] = f2bf(tile[tx][ty + i * 8]);
        }
    }
}

// ---------------------------------------------------------------------------
// Kernel 2: gather + rel max, one wave per row, XCD-aware batch swizzle:
// b = bid & 7 so (with round-robin block->XCD dispatch) each XCD touches only
// one batch's x/yT rows (~2.4 MB hot) -> L2-resident gather.
// (verbatim R15 PASSED)
// ---------------------------------------------------------------------------
__launch_bounds__(256)
__global__ void k_gather_rel(const int* __restrict__ ei, bf16* __restrict__ h,
                             const bf16* __restrict__ yT) {
    const int wave = threadIdx.x >> 6;
    const int lane = threadIdx.x & 63;
    const int b   = blockIdx.x & 7;               // batch pinned per XCD
    const int n   = (blockIdx.x >> 3) * 4 + wave; // 784 groups * 4 waves = 3136
    const int r   = b * N_ + n;

    const int* e0 = ei + (size_t)r * K_;               // edge_index[0] -> gathers y
    const int* e1 = ei + (size_t)BNK + (size_t)r * K_; // edge_index[1] -> gathers x
    int ej[K_], ex[K_];
#pragma unroll
    for (int k = 0; k < K_; k++) { ej[k] = e0[k]; ex[k] = e1[k]; }

    const us4* y4 = (const us4*)(yT + (size_t)b * N_ * C_);   // 48 us4/row
    const us4* x4 = (const us4*)(h + (size_t)b * N_ * KDIM);  // 96 us4/row

    if (lane < 48) {
        float m0 = -3.4e38f, m1 = -3.4e38f, m2 = -3.4e38f, m3 = -3.4e38f;
#pragma unroll
        for (int k = 0; k < K_; k++) {
            us4 vy = y4[(size_t)ej[k] * 48 + lane];
            us4 vx = x4[(size_t)ex[k] * 96 + lane];
            m0 = fmaxf(m0, bfbits2f(vy.x) - bfbits2f(vx.x));
            m1 = fmaxf(m1, bfbits2f(vy.y) - bfbits2f(vx.y));
            m2 = fmaxf(m2, bfbits2f(vy.z) - bfbits2f(vx.z));
            m3 = fmaxf(m3, bfbits2f(vy.w) - bfbits2f(vx.w));
        }
        us4 o;
        o.x = f2bfbits(m0); o.y = f2bfbits(m1);
        o.z = f2bfbits(m2); o.w = f2bfbits(m3);
        *((us4*)(h + (size_t)r * KDIM + C_) + lane) = o;
    }
}

// ---------------------------------------------------------------------------
// Kernel 3: single GEMM pass out_pre[(b,n), o] = sum_k h[(b,n),k] * W[o,k].
// Stores fp32 outp + per-channel sum/sumsq atomics. (verbatim R5 PASSED)
// ---------------------------------------------------------------------------
__launch_bounds__(192)
__global__ void k_gemm(const bf16* __restrict__ h, const bf16* __restrict__ Wb,
                       float* __restrict__ outp, float* __restrict__ stats) {
    int tid = threadIdx.x;
    int wave = tid >> 6, lane = tid & 63;
    int fcol = lane & 15, fgrp = lane >> 4;
    int r0 = blockIdx.x * 64;
    int colbase = wave * 64;

    f32x4 acc[4][4] = {};

    for (int kk = 0; kk < 12; kk++) {
        short8 a[4], bb[4];
#pragma unroll
        for (int i = 0; i < 4; i++)
            a[i] = *reinterpret_cast<const short8*>(
                h + (size_t)(r0 + i * 16 + fcol) * KDIM + kk * 32 + fgrp * 8);
#pragma unroll
        for (int j = 0; j < 4; j++)
            bb[j] = *reinterpret_cast<const short8*>(
                Wb + (size_t)(colbase + j * 16 + fcol) * KDIM + kk * 32 + fgrp * 8);
#pragma unroll
        for (int i = 0; i < 4; i++)
#pragma unroll
            for (int j = 0; j < 4; j++)
                acc[i][j] = __builtin_amdgcn_mfma_f32_16x16x32_bf16(a[i], bb[j], acc[i][j], 0, 0, 0);
    }

#pragma unroll
    for (int j = 0; j < 4; j++) {
        int o = colbase + j * 16 + fcol;
        float s1 = 0.f, s2 = 0.f;
#pragma unroll
        for (int i = 0; i < 4; i++) {
            int rbase = r0 + i * 16 + fgrp * 4;
#pragma unroll
            for (int e = 0; e < 4; e++) {
                float v = acc[i][j][e];
                outp[(size_t)(rbase + e) * OC + o] = v;
                s1 += v;
                s2 += v * v;
            }
        }
        s1 += __shfl_xor(s1, 16); s1 += __shfl_xor(s1, 32);
        s2 += __shfl_xor(s2, 16); s2 += __shfl_xor(s2, 32);
        if (fgrp == 0) {
            atomicAdd(&stats[o], s1);
            atomicAdd(&stats[OC + o], s2);
        }
    }
}

// ---------------------------------------------------------------------------
// Kernel 4: BN (batch stats) + exact GELU, (bn,o) -> (b,o,n) transpose.
// (verbatim R5 PASSED)
// ---------------------------------------------------------------------------
__global__ void k_bn_gelu(const float* __restrict__ outp, const float* __restrict__ stats,
                          const float* __restrict__ gamma, const float* __restrict__ beta,
                          float* __restrict__ out) {
    __shared__ float tile[32][33];
    int tx = threadIdx.x, ty = threadIdx.y;
    int n0 = blockIdx.x * 32, o0 = blockIdx.y * 32, b = blockIdx.z;
#pragma unroll
    for (int i = 0; i < 4; i++) {
        int n = n0 + ty + i * 8;
        tile[ty + i * 8][tx] = outp[(size_t)(b * N_ + n) * OC + o0 + tx];
    }
    __syncthreads();
    const float invc = 1.0f / (float)ROWS;
#pragma unroll
    for (int i = 0; i < 4; i++) {
        int o = o0 + ty + i * 8;
        float mean = stats[o] * invc;
        float var  = stats[OC + o] * invc - mean * mean;
        float is   = rsqrtf(var + 1e-5f);
        float g = gamma[o], bt = beta[o];
        float v = tile[tx][ty + i * 8];
        float z = (v - mean) * is * g + bt;
        float gl = 0.5f * z * (1.0f + erff(z * 0.70710678118654752f));
        out[((size_t)b * OC + o) * N_ + n0 + tx] = gl;
    }
}

// ---------------------------------------------------------------------------
extern "C" void kernel_launch(void* const* d_in, const int* in_sizes, int n_in,
                              void* d_out, int out_size, void* d_ws, size_t ws_size,
                              hipStream_t stream) {
    const float* x     = (const float*)d_in[0];
    const float* y     = (const float*)d_in[1];
    const int*   ei    = (const int*)d_in[2];
    const float* W     = (const float*)d_in[3];
    const float* gamma = (const float*)d_in[4];
    const float* beta  = (const float*)d_in[5];
    float* out = (float*)d_out;

    char* ws = (char*)d_ws;
    // layout:
    //   h     : ROWS*384 bf16 = 19,267,584 B  (first half x, second half rel)
    //   yT    : ROWS*192 bf16 =  9,633,792 B
    //   Wb    : 192*384  bf16 =    147,456 B
    //   stats : 384 fp32      =      1,536 B
    //   outp  : ROWS*192 fp32 = 19,267,584 B
    bf16*  h     = (bf16*)(ws);
    bf16*  yT    = (bf16*)(ws + 19267584);
    bf16*  Wb    = (bf16*)(ws + 28901376);
    float* stats = (float*)(ws + 29048832);
    float* outp  = (float*)(ws + 29050368);

    dim3 bt(32, 8);
    k_prep<<<dim3(N_ / 32, C_ / 32, 2 * B_ + 1), bt, 0, stream>>>(x, y, W, h, yT, Wb, stats);
    k_gather_rel<<<ROWS / 4, 256, 0, stream>>>(ei, h, yT);
    k_gemm<<<ROWS / 64, 192, 0, stream>>>(h, Wb, outp, stats);
    k_bn_gelu<<<dim3(N_ / 32, OC / 32, B_), bt, 0, stream>>>(outp, stats, gamma, beta, out);
}

// Round 17
// 149.213 us; speedup vs baseline: 1.1682x; 1.0014x over previous
//
#include <hip/hip_runtime.h>
#include <hip/hip_bf16.h>

#define B_    8
#define C_    192
#define N_    3136
#define K_    9
#define OC    192
#define KDIM  384                 // 2*C
#define ROWS  (B_ * N_)           // 25088
#define BNK   (B_ * N_ * K_)      // 225792

typedef __hip_bfloat16 bf16;
using short8 = __attribute__((ext_vector_type(8))) short;
using us4    = __attribute__((ext_vector_type(4))) unsigned short;
using f32x4  = __attribute__((ext_vector_type(4))) float;

__device__ inline float bfbits2f(unsigned short u) {
    unsigned int x = ((unsigned int)u) << 16;
    return __builtin_bit_cast(float, x);
}
__device__ inline bf16 f2bf(float v) { return __float2bfloat16(v); }
__device__ inline unsigned short f2bfbits(float v) {
    bf16 t = __float2bfloat16(v);
    return *reinterpret_cast<unsigned short*>(&t);
}

// ---------------------------------------------------------------------------
// Kernel 1: transpose x,y (B,C,N) fp32 -> (B,N,C) bf16, WIDE IO:
// float4 loads along n (16B/lane), us4 bf16 stores along c (8B/lane).
// blockIdx.z==16 slice: W fp32->bf16 and stats zeroing.
// ---------------------------------------------------------------------------
__launch_bounds__(256)
__global__ void k_prep(const float* __restrict__ x, const float* __restrict__ y,
                       const float* __restrict__ W,
                       bf16* __restrict__ h, bf16* __restrict__ yT,
                       bf16* __restrict__ Wb, float* __restrict__ stats) {
    const int tid = threadIdx.x;
    const int bz = blockIdx.z;
    if (bz == 16) {
        int flat = blockIdx.y * 98 + blockIdx.x;
        if (flat < 288) {                       // 288*256 = 73728 = OC*KDIM
            int i = flat * 256 + tid;
            Wb[i] = f2bf(W[i]);
        }
        if (flat == 0 && tid < 192) { stats[tid] = 0.f; stats[192 + tid] = 0.f; }
        return;
    }
    __shared__ float tile[32][33];
    const int n0 = blockIdx.x * 32, c0 = blockIdx.y * 32;
    const int b = bz >> 1, which = bz & 1;
    const float* src = which ? y : x;
    {
        int c_local = tid >> 3, nq = tid & 7;
        float4 v = *reinterpret_cast<const float4*>(
            &src[((size_t)b * C_ + c0 + c_local) * N_ + n0 + nq * 4]);
        tile[c_local][nq * 4 + 0] = v.x;
        tile[c_local][nq * 4 + 1] = v.y;
        tile[c_local][nq * 4 + 2] = v.z;
        tile[c_local][nq * 4 + 3] = v.w;
    }
    __syncthreads();
    {
        int n_local = tid >> 3, cq = tid & 7;
        us4 o;
        o.x = f2bfbits(tile[cq * 4 + 0][n_local]);
        o.y = f2bfbits(tile[cq * 4 + 1][n_local]);
        o.z = f2bfbits(tile[cq * 4 + 2][n_local]);
        o.w = f2bfbits(tile[cq * 4 + 3][n_local]);
        if (which == 0)
            *reinterpret_cast<us4*>(&h[((size_t)b * N_ + n0 + n_local) * KDIM + c0 + cq * 4]) = o;
        else
            *reinterpret_cast<us4*>(&yT[((size_t)b * N_ + n0 + n_local) * C_ + c0 + cq * 4]) = o;
    }
}

// ---------------------------------------------------------------------------
// Kernel 2: gather + rel max, one wave per row, XCD-aware batch swizzle.
// (verbatim R16 PASSED)
// ---------------------------------------------------------------------------
__launch_bounds__(256)
__global__ void k_gather_rel(const int* __restrict__ ei, bf16* __restrict__ h,
                             const bf16* __restrict__ yT) {
    const int wave = threadIdx.x >> 6;
    const int lane = threadIdx.x & 63;
    const int b   = blockIdx.x & 7;               // batch pinned per XCD
    const int n   = (blockIdx.x >> 3) * 4 + wave; // 784 groups * 4 waves = 3136
    const int r   = b * N_ + n;

    const int* e0 = ei + (size_t)r * K_;               // edge_index[0] -> gathers y
    const int* e1 = ei + (size_t)BNK + (size_t)r * K_; // edge_index[1] -> gathers x
    int ej[K_], ex[K_];
#pragma unroll
    for (int k = 0; k < K_; k++) { ej[k] = e0[k]; ex[k] = e1[k]; }

    const us4* y4 = (const us4*)(yT + (size_t)b * N_ * C_);   // 48 us4/row
    const us4* x4 = (const us4*)(h + (size_t)b * N_ * KDIM);  // 96 us4/row

    if (lane < 48) {
        float m0 = -3.4e38f, m1 = -3.4e38f, m2 = -3.4e38f, m3 = -3.4e38f;
#pragma unroll
        for (int k = 0; k < K_; k++) {
            us4 vy = y4[(size_t)ej[k] * 48 + lane];
            us4 vx = x4[(size_t)ex[k] * 96 + lane];
            m0 = fmaxf(m0, bfbits2f(vy.x) - bfbits2f(vx.x));
            m1 = fmaxf(m1, bfbits2f(vy.y) - bfbits2f(vx.y));
            m2 = fmaxf(m2, bfbits2f(vy.z) - bfbits2f(vx.z));
            m3 = fmaxf(m3, bfbits2f(vy.w) - bfbits2f(vx.w));
        }
        us4 o;
        o.x = f2bfbits(m0); o.y = f2bfbits(m1);
        o.z = f2bfbits(m2); o.w = f2bfbits(m3);
        *((us4*)(h + (size_t)r * KDIM + C_) + lane) = o;
    }
}

// ---------------------------------------------------------------------------
// Kernel 3: single GEMM pass out_pre[(b,n), o] = sum_k h[(b,n),k] * W[o,k].
// Stores fp32 outp + per-channel sum/sumsq atomics. (verbatim R16 PASSED)
// ---------------------------------------------------------------------------
__launch_bounds__(192)
__global__ void k_gemm(const bf16* __restrict__ h, const bf16* __restrict__ Wb,
                       float* __restrict__ outp, float* __restrict__ stats) {
    int tid = threadIdx.x;
    int wave = tid >> 6, lane = tid & 63;
    int fcol = lane & 15, fgrp = lane >> 4;
    int r0 = blockIdx.x * 64;
    int colbase = wave * 64;

    f32x4 acc[4][4] = {};

    for (int kk = 0; kk < 12; kk++) {
        short8 a[4], bb[4];
#pragma unroll
        for (int i = 0; i < 4; i++)
            a[i] = *reinterpret_cast<const short8*>(
                h + (size_t)(r0 + i * 16 + fcol) * KDIM + kk * 32 + fgrp * 8);
#pragma unroll
        for (int j = 0; j < 4; j++)
            bb[j] = *reinterpret_cast<const short8*>(
                Wb + (size_t)(colbase + j * 16 + fcol) * KDIM + kk * 32 + fgrp * 8);
#pragma unroll
        for (int i = 0; i < 4; i++)
#pragma unroll
            for (int j = 0; j < 4; j++)
                acc[i][j] = __builtin_amdgcn_mfma_f32_16x16x32_bf16(a[i], bb[j], acc[i][j], 0, 0, 0);
    }

#pragma unroll
    for (int j = 0; j < 4; j++) {
        int o = colbase + j * 16 + fcol;
        float s1 = 0.f, s2 = 0.f;
#pragma unroll
        for (int i = 0; i < 4; i++) {
            int rbase = r0 + i * 16 + fgrp * 4;
#pragma unroll
            for (int e = 0; e < 4; e++) {
                float v = acc[i][j][e];
                outp[(size_t)(rbase + e) * OC + o] = v;
                s1 += v;
                s2 += v * v;
            }
        }
        s1 += __shfl_xor(s1, 16); s1 += __shfl_xor(s1, 32);
        s2 += __shfl_xor(s2, 16); s2 += __shfl_xor(s2, 32);
        if (fgrp == 0) {
            atomicAdd(&stats[o], s1);
            atomicAdd(&stats[OC + o], s2);
        }
    }
}

// ---------------------------------------------------------------------------
// Kernel 4: BN + exact GELU, (bn,o) -> (b,o,n), WIDE IO:
// float4 loads along o, float4 stores along n; BN coeffs once per thread.
// ---------------------------------------------------------------------------
__launch_bounds__(256)
__global__ void k_bn_gelu(const float* __restrict__ outp, const float* __restrict__ stats,
                          const float* __restrict__ gamma, const float* __restrict__ beta,
                          float* __restrict__ out) {
    __shared__ float tile[32][33];
    const int tid = threadIdx.x;
    const int n0 = blockIdx.x * 32, o0 = blockIdx.y * 32, b = blockIdx.z;
    {
        int n_local = tid >> 3, oq = tid & 7;
        float4 v = *reinterpret_cast<const float4*>(
            &outp[(size_t)(b * N_ + n0 + n_local) * OC + o0 + oq * 4]);
        tile[oq * 4 + 0][n_local] = v.x;
        tile[oq * 4 + 1][n_local] = v.y;
        tile[oq * 4 + 2][n_local] = v.z;
        tile[oq * 4 + 3][n_local] = v.w;
    }
    __syncthreads();
    const float invc = 1.0f / (float)ROWS;
    {
        int o_local = tid >> 3, nq = tid & 7;
        int o = o0 + o_local;
        float mean = stats[o] * invc;
        float var  = stats[OC + o] * invc - mean * mean;
        float is   = rsqrtf(var + 1e-5f);
        float sc = gamma[o] * is;
        float sh = beta[o] - mean * sc;
        float4 r;
        {
            float z = tile[o_local][nq * 4 + 0] * sc + sh;
            r.x = 0.5f * z * (1.0f + erff(z * 0.70710678118654752f));
            z = tile[o_local][nq * 4 + 1] * sc + sh;
            r.y = 0.5f * z * (1.0f + erff(z * 0.70710678118654752f));
            z = tile[o_local][nq * 4 + 2] * sc + sh;
            r.z = 0.5f * z * (1.0f + erff(z * 0.70710678118654752f));
            z = tile[o_local][nq * 4 + 3] * sc + sh;
            r.w = 0.5f * z * (1.0f + erff(z * 0.70710678118654752f));
        }
        *reinterpret_cast<float4*>(&out[((size_t)b * OC + o) * N_ + n0 + nq * 4]) = r;
    }
}

// ---------------------------------------------------------------------------
extern "C" void kernel_launch(void* const* d_in, const int* in_sizes, int n_in,
                              void* d_out, int out_size, void* d_ws, size_t ws_size,
                              hipStream_t stream) {
    const float* x     = (const float*)d_in[0];
    const float* y     = (const float*)d_in[1];
    const int*   ei    = (const int*)d_in[2];
    const float* W     = (const float*)d_in[3];
    const float* gamma = (const float*)d_in[4];
    const float* beta  = (const float*)d_in[5];
    float* out = (float*)d_out;

    char* ws = (char*)d_ws;
    // layout:
    //   h     : ROWS*384 bf16 = 19,267,584 B  (first half x, second half rel)
    //   yT    : ROWS*192 bf16 =  9,633,792 B
    //   Wb    : 192*384  bf16 =    147,456 B
    //   stats : 384 fp32      =      1,536 B
    //   outp  : ROWS*192 fp32 = 19,267,584 B
    bf16*  h     = (bf16*)(ws);
    bf16*  yT    = (bf16*)(ws + 19267584);
    bf16*  Wb    = (bf16*)(ws + 28901376);
    float* stats = (float*)(ws + 29048832);
    float* outp  = (float*)(ws + 29050368);

    k_prep<<<dim3(N_ / 32, C_ / 32, 2 * B_ + 1), 256, 0, stream>>>(x, y, W, h, yT, Wb, stats);
    k_gather_rel<<<ROWS / 4, 256, 0, stream>>>(ei, h, yT);
    k_gemm<<<ROWS / 64, 192, 0, stream>>>(h, Wb, outp, stats);
    k_bn_gelu<<<dim3(N_ / 32, OC / 32, B_), 256, 0, stream>>>(outp, stats, gamma, beta, out);
}